// Round 10
// baseline (235.592 us; speedup 1.0000x reference)
//
#include <hip/hip_runtime.h>
#include <math.h>

namespace {

typedef __bf16 bf16x8 __attribute__((ext_vector_type(8)));
typedef __bf16 bf16x4 __attribute__((ext_vector_type(4)));
typedef float  f32x4  __attribute__((ext_vector_type(4)));
typedef float  f32x2  __attribute__((ext_vector_type(2)));

constexpr int B_      = 65536;
constexpr int OBS_DIM_= 85;
constexpr int NL_     = 5;
constexpr int NT_     = 10;
constexpr int HID_    = 64;
constexpr int NACT_   = 5;
constexpr float ALPHA_= 0.01f;

__device__ __forceinline__ float leaky(float x)    { return fmaf(fminf(x, 0.0f), ALPHA_ - 1.0f, x); }
__device__ __forceinline__ float sigmoidf(float x) { return 1.0f / (1.0f + __expf(-x)); }
__device__ __forceinline__ float tanh_fast(float x){ return 1.0f - 2.0f / (__expf(2.0f * x) + 1.0f); }

// 16-lane all-reduce sum on the VALU pipe (DPP within a 16-lane row).
template <int CTRL>
__device__ __forceinline__ float dppadd(float x) {
  int y = __builtin_amdgcn_update_dpp(0, __float_as_int(x), CTRL, 0xF, 0xF, true);
  return x + __int_as_float(y);
}
__device__ __forceinline__ float red16(float x) {
  x = dppadd<0xB1>(x);    // quad_perm xor1
  x = dppadd<0x4E>(x);    // quad_perm xor2
  x = dppadd<0x141>(x);   // row_half_mirror
  x = dppadd<0x140>(x);   // row_mirror
  return x;
}

// ---------------------------------------------------------------------------
// Prep. ws layout (bytes):
//   [0,512)       Wa f32[128]  (W@a twice)
//   [512,+24576)  Wih bf16 (col-permuted: row nt*16+l = orig 4l+nt per gate)
//   [...,+24576)  Whh bf16 (same permutation)
//   [...,+12288)  Wf1T bf16 [64][96] -- K matches s_oin layout:
//                 k<76: w_fc1 row 4+k; 76..79: rows 0..3; 80..84: rows k;
//                 88..92: rows 85..89 (o5); else 0.
// ---------------------------------------------------------------------------
__global__ void prep_kernel(const float* __restrict__ W, const float* __restrict__ a,
                            const float* __restrict__ w_ih, const float* __restrict__ w_hh,
                            const float* __restrict__ w_fc1, void* __restrict__ ws) {
  float* Wa   = (float*)ws;
  __bf16* ih  = (__bf16*)((char*)ws + 512);
  __bf16* hh  = ih + 192 * 64;
  __bf16* f1t = hh + 192 * 64;
  const int tid = blockIdx.x * 256 + threadIdx.x;
  if (blockIdx.x == 0 && threadIdx.x < 64) {
    const int i = threadIdx.x;
    float s1 = 0.0f, s2 = 0.0f;
    #pragma unroll
    for (int j = 0; j < 64; ++j) {
      float w = W[i * 64 + j];
      s1 += w * a[j];
      s2 += w * a[64 + j];
    }
    Wa[i] = s1;
    Wa[64 + i] = s2;
  }
  const int stride = gridDim.x * 256;
  for (int i = tid; i < 192 * 64; i += stride) {
    int pr = i >> 6, k = i & 63;
    int g  = pr >> 6;
    int q  = pr & 63;
    int orig = (g << 6) + ((q & 15) << 2) + (q >> 4);   // 4*l + nt
    ih[i] = (__bf16)w_ih[orig * 64 + k];
    hh[i] = (__bf16)w_hh[orig * 64 + k];
  }
  for (int i = tid; i < 64 * 96; i += stride) {
    int n = i / 96, k = i - 96 * n;
    float v = 0.0f;
    if (k < 76)                 v = w_fc1[(4 + k) * 64 + n];
    else if (k < 80)            v = w_fc1[(k - 76) * 64 + n];
    else if (k < 85)            v = w_fc1[k * 64 + n];
    else if (k >= 88 && k < 93) v = w_fc1[(85 + k - 88) * 64 + n];
    f1t[i] = (__bf16)v;
  }
}

// ======================= FUSED KERNEL =======================
// r21: stage-1-MFMA arc closed (r19 113us, r20 100us vs r17's 81 -- the
// MFMA->VALU round-trip + AGPR banishment is structural at this occupancy).
// Revert stage-1 to the r17 VALU form, now reading the r19 s_oin rotated
// layout (obs_in[t][f] = s_oin[row*96 + t*8 + f]: ONE bf16x8 per t).
// Occupancy theory: CSV VGPR_Count is ARCH only; r17's unified demand was
// ~108 arch + ~64 accum = 172 > 2048/12 -> only 2 blocks/CU resident, and
// (256,3)'s 170 cap spilled by exactly the overshoot. Fix the demand, not
// the bound: GRU phase A split over nt-halves (accum peak 32 -> 16,
// per-accumulator MFMA order unchanged) -> unified ~124-140, then
// __launch_bounds__(256,3) fits spill-free -> 3+ blocks/CU.
constexpr int SXH_ = 72;

__global__ __launch_bounds__(256, 3) void fused_kernel(
    const float* __restrict__ obs, const float* __restrict__ hidden,
    const float* __restrict__ w_in0, const float* __restrict__ b_in0,
    const float* __restrict__ w_in1, const float* __restrict__ b_in1,
    const float* __restrict__ w_in2, const float* __restrict__ b_in2,
    const float* __restrict__ w_o1, const float* __restrict__ b_o1,
    const float* __restrict__ w_o2, const float* __restrict__ b_o2,
    const float* __restrict__ w_o3, const float* __restrict__ b_o3,
    const float* __restrict__ b_fc1,
    const float* __restrict__ b_ih, const float* __restrict__ b_hh,
    const float* __restrict__ w_fc2, const float* __restrict__ b_fc2,
    const void* __restrict__ wsv,
    float* __restrict__ q_out, float* __restrict__ h_out) {

  __shared__ __align__(16) char smem[33024];
  __bf16* s_oin          = (__bf16*)smem;                       // [64][96]
  float (*s_wh1)[12]     = (float (*)[12])(smem + 12288);       // [64][12]
  float (*s_wh2)[12]     = (float (*)[12])(smem + 15360);       // [64][12]
  float  (*s_att)[5][10] = (float (*)[5][10])(smem + 18432);    // [16][5][10]
  __bf16 (*s_h1)[5][32]  = (__bf16 (*)[5][32])(smem + 21632);
  float  (*s_h2)[5][16]  = (float (*)[5][16])(smem + 26752);
  float (*s_colm)[6]     = (float (*)[6])(smem + 31872);
  float (*s_cols)[6]     = (float (*)[6])(smem + 32256);
  float (*s_hp)[6]       = (float (*)[6])(smem + 32640);
  __bf16* A_x            = (__bf16*)(smem + 18432);             // union w/ front scratch

  const int tid  = threadIdx.x;
  const int wv   = tid >> 6;
  const int lane = tid & 63;
  const int l16  = lane & 15;
  const int quad = lane >> 4;
  const int grp  = tid >> 4;               // 0..15 (row group within a pass)
  const int r0   = wv * 16;
  const long gr0 = (long)blockIdx.x * 64;

  const float* Wa = (const float*)wsv;
  const __bf16* Wih = (const __bf16*)((const char*)wsv + 512);
  const __bf16* Whh = Wih + 192 * 64;
  const __bf16* Wf1 = Whh + 192 * 64;

  // ---- stage: obs rows -> bf16 s_oin in obs_in order ----
  {
    const float* src = obs + gr0 * OBS_DIM_;
    const int base = wv * 340;
    #pragma unroll
    for (int k = 0; k < 6; ++k) {
      if (k < 5 || lane < 20) {
        int c4 = base + k * 64 + lane;
        f32x4 v = *(const f32x4*)&src[c4 * 4];
        #pragma unroll
        for (int e = 0; e < 4; ++e) {
          int fe = c4 * 4 + e;
          int r = fe / 85, c = fe - 85 * r;
          int j = (c < 4) ? (76 + c) : ((c >= 80) ? c : (c - 4));
          s_oin[r * 96 + j] = (__bf16)v[e];
        }
      }
    }
    for (int i2 = tid; i2 < 704; i2 += 256) {      // zero j=85..95 (incl o5 slot)
      int r = i2 / 11, j = 85 + i2 % 11;
      s_oin[r * 96 + j] = (__bf16)0.0f;
    }
  }

  const int u0 = l16 * 4;
  const f32x4 wa1 = *(const f32x4*)&Wa[u0];
  const f32x4 wa2 = *(const f32x4*)&Wa[64 + u0];

  __syncthreads();

  // ================= FRONT PHASE: 4 passes x 16 rows =================
  #pragma unroll 1
  for (int pass = 0; pass < 4; ++pass) {
    const int row = pass * 16 + grp;                 // block-local row 0..63
    const __bf16* orow = s_oin + row * 96;

    // stage-1 (VALU): wh1/wh2 for this row; one bf16x8 read per t
    f32x4 wA[8];
    f32x4 bA;
    #pragma unroll
    for (int t = 0; t < NT_; ++t) {
      if (t == 0) {
        #pragma unroll
        for (int f = 0; f < 8; ++f) wA[f] = *(const f32x4*)&w_in0[f * 64 + u0];
        bA = *(const f32x4*)&b_in0[u0];
      }
      if (t == 5) {
        #pragma unroll
        for (int f = 0; f < 8; ++f) wA[f] = *(const f32x4*)&w_in1[f * 64 + u0];
        bA = *(const f32x4*)&b_in1[u0];
      }
      if (t == 9) {
        #pragma unroll
        for (int f = 0; f < 8; ++f) wA[f] = *(const f32x4*)&w_in2[f * 64 + u0];
        bA = *(const f32x4*)&b_in2[u0];
      }
      bf16x8 v8 = *(const bf16x8*)&orow[t * 8];
      float ov[8];
      #pragma unroll
      for (int e = 0; e < 8; ++e) ov[e] = (float)v8[e];
      f32x4 z = bA;
      #pragma unroll
      for (int f = 0; f < 8; ++f) {
        z[0] += ov[f] * wA[f][0]; z[1] += ov[f] * wA[f][1];
        z[2] += ov[f] * wA[f][2]; z[3] += ov[f] * wA[f][3];
      }
      float h0 = leaky(z[0]), h1 = leaky(z[1]), h2 = leaky(z[2]), h3 = leaky(z[3]);
      float p1t = h0 * wa1[0] + h1 * wa1[1] + h2 * wa1[2] + h3 * wa1[3];
      float p2t = h0 * wa2[0] + h1 * wa2[1] + h2 * wa2[2] + h3 * wa2[3];
      p1t = red16(p1t);
      p2t = red16(p2t);
      if (l16 == 0) { s_wh1[row][t] = p1t; s_wh2[row][t] = p2t; }
    }

    // att1 column softmax stats (lanes 5..9)
    if (l16 >= 5 && l16 < 10) {
      const int jj = l16 - 5;
      float w1v = s_wh1[row][NL_ + jj];
      float ev[NL_], m = -1e30f;
      #pragma unroll
      for (int k = 0; k < NL_; ++k) { ev[k] = leaky(w1v + s_wh2[row][k]); m = fmaxf(m, ev[k]); }
      float s = 0.0f;
      #pragma unroll
      for (int k = 0; k < NL_; ++k) s += __expf(ev[k] - m);
      s_colm[grp][jj] = m;
      s_cols[grp][jj] = s;
    }

    // attention rows (lanes 0..4)
    if (l16 < NL_) {
      const int r = l16;
      const float wh1_r = s_wh1[row][r];
      const float wh2_r = s_wh2[row][r];
      float ev[NL_], m = -1e30f;
      #pragma unroll
      for (int j = 0; j < NL_; ++j) { ev[j] = leaky(wh1_r + s_wh2[row][NL_ + j]); m = fmaxf(m, ev[j]); }
      float a0[NL_], s = 0.0f;
      #pragma unroll
      for (int j = 0; j < NL_; ++j) { a0[j] = __expf(ev[j] - m); s += a0[j]; }
      float inv = 1.0f / s;
      #pragma unroll
      for (int j = 0; j < NL_; ++j) s_att[grp][r][j] = a0[j] * inv;
      #pragma unroll
      for (int jj = 0; jj < NL_; ++jj) {
        float e = leaky(s_wh1[row][NL_ + jj] + wh2_r);
        s_att[grp][r][NL_ + jj] = __expf(e - s_colm[grp][jj]) / s_cols[grp][jj];
      }
    }

    // h1: lane owns units 2*l16, 2*l16+1 (stored bf16)
    {
      f32x2 w1c[NT_];
      #pragma unroll
      for (int k = 0; k < NT_; ++k) w1c[k] = *(const f32x2*)&w_o1[k * 32 + l16 * 2];
      const f32x2 b1 = *(const f32x2*)&b_o1[l16 * 2];
      #pragma unroll
      for (int r5 = 0; r5 < NL_; ++r5) {
        float za = b1[0], zb = b1[1];
        #pragma unroll
        for (int k2 = 0; k2 < 5; ++k2) {
          f32x2 at = *(const f32x2*)&s_att[grp][r5][k2 * 2];
          za += at[0] * w1c[2 * k2][0] + at[1] * w1c[2 * k2 + 1][0];
          zb += at[0] * w1c[2 * k2][1] + at[1] * w1c[2 * k2 + 1][1];
        }
        s_h1[grp][r5][l16 * 2]     = (__bf16)leaky(za);
        s_h1[grp][r5][l16 * 2 + 1] = (__bf16)leaky(zb);
      }
    }

    // h2: lane owns unit l16
    {
      float w2c[32];
      #pragma unroll
      for (int k = 0; k < 32; ++k) w2c[k] = w_o2[k * 16 + l16];
      const float b2 = b_o2[l16];
      #pragma unroll
      for (int r5 = 0; r5 < NL_; ++r5) {
        float z = b2;
        #pragma unroll
        for (int k4 = 0; k4 < 8; ++k4) {
          bf16x4 hv = *(const bf16x4*)&s_h1[grp][r5][k4 * 4];
          z += (float)hv[0] * w2c[4 * k4] + (float)hv[1] * w2c[4 * k4 + 1]
             + (float)hv[2] * w2c[4 * k4 + 2] + (float)hv[3] * w2c[4 * k4 + 3];
        }
        s_h2[grp][r5][l16] = leaky(z);
      }
    }

    // hp + softmax -> o5 slot in s_oin (lanes 0..4)
    if (l16 < NL_) {
      float z3 = b_o3[0];
      #pragma unroll
      for (int k4 = 0; k4 < 4; ++k4) {
        f32x4 hv = *(const f32x4*)&s_h2[grp][l16][k4 * 4];
        z3 += hv[0] * w_o3[4 * k4] + hv[1] * w_o3[4 * k4 + 1]
            + hv[2] * w_o3[4 * k4 + 2] + hv[3] * w_o3[4 * k4 + 3];
      }
      float hp_own = leaky(z3);
      s_hp[grp][l16] = hp_own;
      float m5 = -1e30f;
      #pragma unroll
      for (int j = 0; j < NL_; ++j) m5 = fmaxf(m5, s_hp[grp][j]);
      float ssum = 0.0f;
      #pragma unroll
      for (int j = 0; j < NL_; ++j) ssum += __expf(s_hp[grp][j] - m5);
      s_oin[row * 96 + 88 + l16] = (__bf16)(__expf(hp_own - m5) / ssum);
    }
  }

  __syncthreads();   // o5 ready; front scratch dead -> A_x may overwrite

  // ================= GEMM PHASE: wave wv owns rows r0..r0+15 =================
  const int l = l16;

  // hidden A-fragments direct from global
  bf16x8 ah[2];
  {
    const float* hrow_g = hidden + (gr0 + r0 + l) * HID_;
    f32x4 vha0 = *(const f32x4*)&hrow_g[quad * 8];
    f32x4 vha1 = *(const f32x4*)&hrow_g[quad * 8 + 4];
    f32x4 vhb0 = *(const f32x4*)&hrow_g[32 + quad * 8];
    f32x4 vhb1 = *(const f32x4*)&hrow_g[32 + quad * 8 + 4];
    bf16x8 t;
    t[0] = (__bf16)vha0[0]; t[1] = (__bf16)vha0[1]; t[2] = (__bf16)vha0[2]; t[3] = (__bf16)vha0[3];
    t[4] = (__bf16)vha1[0]; t[5] = (__bf16)vha1[1]; t[6] = (__bf16)vha1[2]; t[7] = (__bf16)vha1[3];
    ah[0] = t;
    t[0] = (__bf16)vhb0[0]; t[1] = (__bf16)vhb0[1]; t[2] = (__bf16)vhb0[2]; t[3] = (__bf16)vhb0[3];
    t[4] = (__bf16)vhb1[0]; t[5] = (__bf16)vhb1[1]; t[6] = (__bf16)vhb1[2]; t[7] = (__bf16)vhb1[3];
    ah[1] = t;
  }

  const f32x4 zero4 = {0.0f, 0.0f, 0.0f, 0.0f};

  // fc1: C[16x64] = s_oin[16x96] @ Wf1T -- all A-frags single aligned b128.
  f32x4 cx[4];
  #pragma unroll
  for (int nt = 0; nt < 4; ++nt) cx[nt] = zero4;
  #pragma unroll
  for (int ks = 0; ks < 3; ++ks) {
    bf16x8 af = *(const bf16x8*)&s_oin[(r0 + l) * 96 + ks * 32 + quad * 8];
    #pragma unroll
    for (int nt = 0; nt < 4; ++nt) {
      bf16x8 bf = *(const bf16x8*)&Wf1[(nt * 16 + l) * 96 + ks * 32 + quad * 8];
      cx[nt] = __builtin_amdgcn_mfma_f32_16x16x32_bf16(af, bf, cx[nt], 0, 0, 0);
    }
  }
  #pragma unroll
  for (int nt = 0; nt < 4; ++nt) {
    float bias = b_fc1[nt * 16 + l];
    #pragma unroll
    for (int rg = 0; rg < 4; ++rg) {
      float xv = fmaxf(cx[nt][rg] + bias, 0.0f);
      A_x[(r0 + quad * 4 + rg) * SXH_ + nt * 16 + l] = (__bf16)xv;
    }
  }

  // GRU GEMMs, gate-split (B-columns permuted: tile nt, lane l == orig col 4l+nt)
  bf16x8 ax[2];
  #pragma unroll
  for (int ks = 0; ks < 2; ++ks)
    ax[ks] = *(const bf16x8*)&A_x[(r0 + l) * SXH_ + ks * 32 + quad * 8];

  // ---- phase A (nt-split halves, accum peak 16): r-gates + gh_n -> rn ----
  f32x4 rn[4];
  {
    f32x4 a0 = *(const f32x4*)&b_ih[4 * l];
    f32x4 a1 = *(const f32x4*)&b_hh[4 * l];
    f32x4 br4 = a0 + a1;
    f32x4 bhn4 = *(const f32x4*)&b_hh[128 + 4 * l];
    #pragma unroll
    for (int hf = 0; hf < 2; ++hf) {
      f32x4 cr2[2], ch2[2];
      cr2[0] = zero4; cr2[1] = zero4; ch2[0] = zero4; ch2[1] = zero4;
      #pragma unroll
      for (int n2 = 0; n2 < 2; ++n2) {
        const int nt = hf * 2 + n2;
        #pragma unroll
        for (int ks = 0; ks < 2; ++ks) {
          bf16x8 bi = *(const bf16x8*)&Wih[(nt * 16 + l) * 64 + ks * 32 + quad * 8];
          cr2[n2] = __builtin_amdgcn_mfma_f32_16x16x32_bf16(ax[ks], bi, cr2[n2], 0, 0, 0);
          bf16x8 bh = *(const bf16x8*)&Whh[(nt * 16 + l) * 64 + ks * 32 + quad * 8];
          cr2[n2] = __builtin_amdgcn_mfma_f32_16x16x32_bf16(ah[ks], bh, cr2[n2], 0, 0, 0);
        }
        #pragma unroll
        for (int ks = 0; ks < 2; ++ks) {
          bf16x8 bh = *(const bf16x8*)&Whh[(128 + nt * 16 + l) * 64 + ks * 32 + quad * 8];
          ch2[n2] = __builtin_amdgcn_mfma_f32_16x16x32_bf16(ah[ks], bh, ch2[n2], 0, 0, 0);
        }
      }
      #pragma unroll
      for (int n2 = 0; n2 < 2; ++n2) {
        const int nt = hf * 2 + n2;
        #pragma unroll
        for (int rg = 0; rg < 4; ++rg) {
          float rr = sigmoidf(cr2[n2][rg] + br4[nt]);
          rn[nt][rg] = rr * (ch2[n2][rg] + bhn4[nt]);
        }
      }
    }
  }

  // ---- phase B: gi_n; retire into nn ----
  f32x4 cn[4];
  #pragma unroll
  for (int nt = 0; nt < 4; ++nt) cn[nt] = zero4;
  #pragma unroll
  for (int nt = 0; nt < 4; ++nt)
    #pragma unroll
    for (int ks = 0; ks < 2; ++ks) {
      bf16x8 bi = *(const bf16x8*)&Wih[(128 + nt * 16 + l) * 64 + ks * 32 + quad * 8];
      cn[nt] = __builtin_amdgcn_mfma_f32_16x16x32_bf16(ax[ks], bi, cn[nt], 0, 0, 0);
    }
  f32x4 nn[4];
  {
    f32x4 bin4 = *(const f32x4*)&b_ih[128 + 4 * l];
    #pragma unroll
    for (int nt = 0; nt < 4; ++nt)
      #pragma unroll
      for (int rg = 0; rg < 4; ++rg)
        nn[nt][rg] = tanh_fast(cn[nt][rg] + bin4[nt] + rn[nt][rg]);
  }

  // ---- phase C: z-gates, then h / q (per-rg retire) ----
  f32x4 cz[4];
  #pragma unroll
  for (int nt = 0; nt < 4; ++nt) cz[nt] = zero4;
  #pragma unroll
  for (int nt = 0; nt < 4; ++nt)
    #pragma unroll
    for (int ks = 0; ks < 2; ++ks) {
      bf16x8 bi = *(const bf16x8*)&Wih[(64 + nt * 16 + l) * 64 + ks * 32 + quad * 8];
      cz[nt] = __builtin_amdgcn_mfma_f32_16x16x32_bf16(ax[ks], bi, cz[nt], 0, 0, 0);
      bf16x8 bh = *(const bf16x8*)&Whh[(64 + nt * 16 + l) * 64 + ks * 32 + quad * 8];
      cz[nt] = __builtin_amdgcn_mfma_f32_16x16x32_bf16(ah[ks], bh, cz[nt], 0, 0, 0);
    }

  const long grow = gr0 + r0 + quad * 4;
  f32x4 bz4;
  {
    f32x4 a0 = *(const f32x4*)&b_ih[64 + 4 * l];
    f32x4 a1 = *(const f32x4*)&b_hh[64 + 4 * l];
    bz4 = a0 + a1;
  }
  f32x4 w20[5];
  #pragma unroll
  for (int j = 0; j < 5; ++j) w20[j] = *(const f32x4*)&w_fc2[20 * l + 4 * j];

  #pragma unroll
  for (int rg = 0; rg < 4; ++rg) {
    f32x4 hold = *(const f32x4*)&hidden[(grow + rg) * HID_ + 4 * l];
    f32x4 hnew;
    float qp5[NACT_] = {0.0f, 0.0f, 0.0f, 0.0f, 0.0f};
    #pragma unroll
    for (int t = 0; t < 4; ++t) {
      float zz = sigmoidf(cz[t][rg] + bz4[t]);
      float hn = (1.0f - zz) * nn[t][rg] + zz * hold[t];
      hnew[t] = hn;
      #pragma unroll
      for (int c = 0; c < NACT_; ++c)
        qp5[c] += hn * w20[(5 * t + c) >> 2][(5 * t + c) & 3];
    }
    *(f32x4*)&h_out[(grow + rg) * HID_ + 4 * l] = hnew;
    #pragma unroll
    for (int c = 0; c < NACT_; ++c) qp5[c] = red16(qp5[c]);
    if (l < NACT_) {
      float qv = qp5[0];
      if (l == 1) qv = qp5[1];
      if (l == 2) qv = qp5[2];
      if (l == 3) qv = qp5[3];
      if (l == 4) qv = qp5[4];
      q_out[(grow + rg) * NACT_ + l] = qv + b_fc2[l];
    }
  }
}

}  // namespace

extern "C" void kernel_launch(void* const* d_in, const int* in_sizes, int n_in,
                              void* d_out, int out_size, void* d_ws, size_t ws_size,
                              hipStream_t stream) {
  const float* obs    = (const float*)d_in[0];
  const float* hidden = (const float*)d_in[1];
  const float* w_in0  = (const float*)d_in[2];
  const float* b_in0  = (const float*)d_in[3];
  const float* w_in1  = (const float*)d_in[4];
  const float* b_in1  = (const float*)d_in[5];
  const float* w_in2  = (const float*)d_in[6];
  const float* b_in2  = (const float*)d_in[7];
  const float* W      = (const float*)d_in[8];
  const float* a      = (const float*)d_in[9];
  const float* w_o1   = (const float*)d_in[10];
  const float* b_o1   = (const float*)d_in[11];
  const float* w_o2   = (const float*)d_in[12];
  const float* b_o2   = (const float*)d_in[13];
  const float* w_o3   = (const float*)d_in[14];
  const float* b_o3   = (const float*)d_in[15];
  const float* w_fc1  = (const float*)d_in[16];
  const float* b_fc1  = (const float*)d_in[17];
  const float* w_ih   = (const float*)d_in[18];
  const float* w_hh   = (const float*)d_in[19];
  const float* b_ih   = (const float*)d_in[20];
  const float* b_hh   = (const float*)d_in[21];
  const float* w_fc2  = (const float*)d_in[22];
  const float* b_fc2  = (const float*)d_in[23];

  float* q_out = (float*)d_out;                  // (B,5)
  float* h_out = q_out + (long)B_ * NACT_;       // (B,64)

  prep_kernel<<<48, 256, 0, stream>>>(W, a, w_ih, w_hh, w_fc1, d_ws);
  fused_kernel<<<B_ / 64, 256, 0, stream>>>(
      obs, hidden,
      w_in0, b_in0, w_in1, b_in1, w_in2, b_in2,
      w_o1, b_o1, w_o2, b_o2, w_o3, b_o3,
      b_fc1, b_ih, b_hh, w_fc2, b_fc2,
      d_ws, q_out, h_out);
}

// Round 11
// 203.795 us; speedup vs baseline: 1.1560x; 1.1560x over previous
//
#include <hip/hip_runtime.h>
#include <math.h>

namespace {

typedef __bf16 bf16x8 __attribute__((ext_vector_type(8)));
typedef __bf16 bf16x4 __attribute__((ext_vector_type(4)));
typedef float  f32x4  __attribute__((ext_vector_type(4)));
typedef float  f32x2  __attribute__((ext_vector_type(2)));

constexpr int B_      = 65536;
constexpr int OBS_DIM_= 85;
constexpr int NL_     = 5;
constexpr int NT_     = 10;
constexpr int HID_    = 64;
constexpr int NACT_   = 5;
constexpr float ALPHA_= 0.01f;

__device__ __forceinline__ float leaky(float x)    { return fmaf(fminf(x, 0.0f), ALPHA_ - 1.0f, x); }
__device__ __forceinline__ float sigmoidf(float x) { return 1.0f / (1.0f + __expf(-x)); }
__device__ __forceinline__ float tanh_fast(float x){ return 1.0f - 2.0f / (__expf(2.0f * x) + 1.0f); }

// 16-lane all-reduce sum on the VALU pipe (DPP within a 16-lane row).
template <int CTRL>
__device__ __forceinline__ float dppadd(float x) {
  int y = __builtin_amdgcn_update_dpp(0, __float_as_int(x), CTRL, 0xF, 0xF, true);
  return x + __int_as_float(y);
}
__device__ __forceinline__ float red16(float x) {
  x = dppadd<0xB1>(x);    // quad_perm xor1
  x = dppadd<0x4E>(x);    // quad_perm xor2
  x = dppadd<0x141>(x);   // row_half_mirror
  x = dppadd<0x140>(x);   // row_mirror
  return x;
}

// ---------------------------------------------------------------------------
// Prep. ws layout (bytes):
//   [0,512)       Wa f32[128]  (W@a twice)
//   [512,+24576)  Wih bf16 (col-permuted: row nt*16+l = orig 4l+nt per gate)
//   [...,+24576)  Whh bf16 (same permutation)
//   [...,+12288)  Wf1T bf16 [64][96] -- K matches s_oin layout:
//                 k<76: w_fc1 row 4+k; 76..79: rows 0..3; 80..84: rows k;
//                 88..92: rows 85..89 (o5); else 0.
// ---------------------------------------------------------------------------
__global__ void prep_kernel(const float* __restrict__ W, const float* __restrict__ a,
                            const float* __restrict__ w_ih, const float* __restrict__ w_hh,
                            const float* __restrict__ w_fc1, void* __restrict__ ws) {
  float* Wa   = (float*)ws;
  __bf16* ih  = (__bf16*)((char*)ws + 512);
  __bf16* hh  = ih + 192 * 64;
  __bf16* f1t = hh + 192 * 64;
  const int tid = blockIdx.x * 256 + threadIdx.x;
  if (blockIdx.x == 0 && threadIdx.x < 64) {
    const int i = threadIdx.x;
    float s1 = 0.0f, s2 = 0.0f;
    #pragma unroll
    for (int j = 0; j < 64; ++j) {
      float w = W[i * 64 + j];
      s1 += w * a[j];
      s2 += w * a[64 + j];
    }
    Wa[i] = s1;
    Wa[64 + i] = s2;
  }
  const int stride = gridDim.x * 256;
  for (int i = tid; i < 192 * 64; i += stride) {
    int pr = i >> 6, k = i & 63;
    int g  = pr >> 6;
    int q  = pr & 63;
    int orig = (g << 6) + ((q & 15) << 2) + (q >> 4);   // 4*l + nt
    ih[i] = (__bf16)w_ih[orig * 64 + k];
    hh[i] = (__bf16)w_hh[orig * 64 + k];
  }
  for (int i = tid; i < 64 * 96; i += stride) {
    int n = i / 96, k = i - 96 * n;
    float v = 0.0f;
    if (k < 76)                 v = w_fc1[(4 + k) * 64 + n];
    else if (k < 80)            v = w_fc1[(k - 76) * 64 + n];
    else if (k < 85)            v = w_fc1[k * 64 + n];
    else if (k >= 88 && k < 93) v = w_fc1[(85 + k - 88) * 64 + n];
    f1t[i] = (__bf16)v;
  }
}

// ======================= FUSED KERNEL =======================
// r22: occupancy avenue CLOSED -- empirical: (256,2)=108regs/no-spill/81us,
// (256,3)=spill (r14 84MB, r21 55MB), (256,4)=heavy spill. Allocator floor
// ~108 arch + accums; tighter bounds only buy scratch traffic. Final bound:
// (256,2). Remaining lever = VALU issue count + DPP-chain latency in
// stage-1 (75% of ~3500 insts/thread). Change: stage-1 HOISTED out of the
// pass loop; each group processes its 4 rows interleaved per t -> 8
// independent red16 chains in flight (DPP latency hidden by ILP) and wA
// class-weight loads drop 4x (96 -> 24/thread). Numerics identical per row.
constexpr int SXH_ = 72;

__global__ __launch_bounds__(256, 2) void fused_kernel(
    const float* __restrict__ obs, const float* __restrict__ hidden,
    const float* __restrict__ w_in0, const float* __restrict__ b_in0,
    const float* __restrict__ w_in1, const float* __restrict__ b_in1,
    const float* __restrict__ w_in2, const float* __restrict__ b_in2,
    const float* __restrict__ w_o1, const float* __restrict__ b_o1,
    const float* __restrict__ w_o2, const float* __restrict__ b_o2,
    const float* __restrict__ w_o3, const float* __restrict__ b_o3,
    const float* __restrict__ b_fc1,
    const float* __restrict__ b_ih, const float* __restrict__ b_hh,
    const float* __restrict__ w_fc2, const float* __restrict__ b_fc2,
    const void* __restrict__ wsv,
    float* __restrict__ q_out, float* __restrict__ h_out) {

  __shared__ __align__(16) char smem[33024];
  __bf16* s_oin          = (__bf16*)smem;                       // [64][96]
  float (*s_wh1)[12]     = (float (*)[12])(smem + 12288);       // [64][12]
  float (*s_wh2)[12]     = (float (*)[12])(smem + 15360);       // [64][12]
  float  (*s_att)[5][10] = (float (*)[5][10])(smem + 18432);    // [16][5][10]
  __bf16 (*s_h1)[5][32]  = (__bf16 (*)[5][32])(smem + 21632);
  float  (*s_h2)[5][16]  = (float (*)[5][16])(smem + 26752);
  float (*s_colm)[6]     = (float (*)[6])(smem + 31872);
  float (*s_cols)[6]     = (float (*)[6])(smem + 32256);
  float (*s_hp)[6]       = (float (*)[6])(smem + 32640);
  __bf16* A_x            = (__bf16*)(smem + 18432);             // union w/ front scratch

  const int tid  = threadIdx.x;
  const int wv   = tid >> 6;
  const int lane = tid & 63;
  const int l16  = lane & 15;
  const int quad = lane >> 4;
  const int grp  = tid >> 4;               // 0..15 (row group)
  const int r0   = wv * 16;
  const long gr0 = (long)blockIdx.x * 64;

  const float* Wa = (const float*)wsv;
  const __bf16* Wih = (const __bf16*)((const char*)wsv + 512);
  const __bf16* Whh = Wih + 192 * 64;
  const __bf16* Wf1 = Whh + 192 * 64;

  // ---- stage: obs rows -> bf16 s_oin in obs_in order ----
  {
    const float* src = obs + gr0 * OBS_DIM_;
    const int base = wv * 340;
    #pragma unroll
    for (int k = 0; k < 6; ++k) {
      if (k < 5 || lane < 20) {
        int c4 = base + k * 64 + lane;
        f32x4 v = *(const f32x4*)&src[c4 * 4];
        #pragma unroll
        for (int e = 0; e < 4; ++e) {
          int fe = c4 * 4 + e;
          int r = fe / 85, c = fe - 85 * r;
          int j = (c < 4) ? (76 + c) : ((c >= 80) ? c : (c - 4));
          s_oin[r * 96 + j] = (__bf16)v[e];
        }
      }
    }
    for (int i2 = tid; i2 < 704; i2 += 256) {      // zero j=85..95 (incl o5 slot)
      int r = i2 / 11, j = 85 + i2 % 11;
      s_oin[r * 96 + j] = (__bf16)0.0f;
    }
  }

  const int u0 = l16 * 4;
  const f32x4 wa1 = *(const f32x4*)&Wa[u0];
  const f32x4 wa2 = *(const f32x4*)&Wa[64 + u0];

  __syncthreads();

  // ===== STAGE-1 (hoisted, 4 rows interleaved): wh1/wh2 for rows r4*16+grp =====
  {
    f32x4 wA[8];
    f32x4 bA;
    #pragma unroll
    for (int t = 0; t < NT_; ++t) {
      if (t == 0) {
        #pragma unroll
        for (int f = 0; f < 8; ++f) wA[f] = *(const f32x4*)&w_in0[f * 64 + u0];
        bA = *(const f32x4*)&b_in0[u0];
      }
      if (t == 5) {
        #pragma unroll
        for (int f = 0; f < 8; ++f) wA[f] = *(const f32x4*)&w_in1[f * 64 + u0];
        bA = *(const f32x4*)&b_in1[u0];
      }
      if (t == 9) {
        #pragma unroll
        for (int f = 0; f < 8; ++f) wA[f] = *(const f32x4*)&w_in2[f * 64 + u0];
        bA = *(const f32x4*)&b_in2[u0];
      }
      float p1[4], p2[4];
      #pragma unroll
      for (int r4 = 0; r4 < 4; ++r4) {
        bf16x8 v8 = *(const bf16x8*)&s_oin[(r4 * 16 + grp) * 96 + t * 8];
        float ov[8];
        #pragma unroll
        for (int e = 0; e < 8; ++e) ov[e] = (float)v8[e];
        f32x4 z = bA;
        #pragma unroll
        for (int f = 0; f < 8; ++f) {
          z[0] += ov[f] * wA[f][0]; z[1] += ov[f] * wA[f][1];
          z[2] += ov[f] * wA[f][2]; z[3] += ov[f] * wA[f][3];
        }
        float h0 = leaky(z[0]), h1 = leaky(z[1]), h2 = leaky(z[2]), h3 = leaky(z[3]);
        p1[r4] = h0 * wa1[0] + h1 * wa1[1] + h2 * wa1[2] + h3 * wa1[3];
        p2[r4] = h0 * wa2[0] + h1 * wa2[1] + h2 * wa2[2] + h3 * wa2[3];
      }
      // 8 independent DPP reduction chains -> latency hidden by ILP
      #pragma unroll
      for (int r4 = 0; r4 < 4; ++r4) { p1[r4] = red16(p1[r4]); p2[r4] = red16(p2[r4]); }
      if (l16 == 0) {
        #pragma unroll
        for (int r4 = 0; r4 < 4; ++r4) {
          s_wh1[r4 * 16 + grp][t] = p1[r4];
          s_wh2[r4 * 16 + grp][t] = p2[r4];
        }
      }
    }
  }
  // s_wh written by l16==0 of each group, read below by lanes of the SAME
  // group (same wave) -> in-wave DS ordering suffices, no barrier needed
  // (same precedent as the per-pass form).

  // ================= FRONT PHASE: 4 passes x 16 rows (att/MLP/softmax) =======
  #pragma unroll 1
  for (int pass = 0; pass < 4; ++pass) {
    const int row = pass * 16 + grp;                 // block-local row 0..63

    // att1 column softmax stats (lanes 5..9)
    if (l16 >= 5 && l16 < 10) {
      const int jj = l16 - 5;
      float w1v = s_wh1[row][NL_ + jj];
      float ev[NL_], m = -1e30f;
      #pragma unroll
      for (int k = 0; k < NL_; ++k) { ev[k] = leaky(w1v + s_wh2[row][k]); m = fmaxf(m, ev[k]); }
      float s = 0.0f;
      #pragma unroll
      for (int k = 0; k < NL_; ++k) s += __expf(ev[k] - m);
      s_colm[grp][jj] = m;
      s_cols[grp][jj] = s;
    }

    // attention rows (lanes 0..4)
    if (l16 < NL_) {
      const int r = l16;
      const float wh1_r = s_wh1[row][r];
      const float wh2_r = s_wh2[row][r];
      float ev[NL_], m = -1e30f;
      #pragma unroll
      for (int j = 0; j < NL_; ++j) { ev[j] = leaky(wh1_r + s_wh2[row][NL_ + j]); m = fmaxf(m, ev[j]); }
      float a0[NL_], s = 0.0f;
      #pragma unroll
      for (int j = 0; j < NL_; ++j) { a0[j] = __expf(ev[j] - m); s += a0[j]; }
      float inv = 1.0f / s;
      #pragma unroll
      for (int j = 0; j < NL_; ++j) s_att[grp][r][j] = a0[j] * inv;
      #pragma unroll
      for (int jj = 0; jj < NL_; ++jj) {
        float e = leaky(s_wh1[row][NL_ + jj] + wh2_r);
        s_att[grp][r][NL_ + jj] = __expf(e - s_colm[grp][jj]) / s_cols[grp][jj];
      }
    }

    // h1: lane owns units 2*l16, 2*l16+1 (stored bf16)
    {
      f32x2 w1c[NT_];
      #pragma unroll
      for (int k = 0; k < NT_; ++k) w1c[k] = *(const f32x2*)&w_o1[k * 32 + l16 * 2];
      const f32x2 b1 = *(const f32x2*)&b_o1[l16 * 2];
      #pragma unroll
      for (int r5 = 0; r5 < NL_; ++r5) {
        float za = b1[0], zb = b1[1];
        #pragma unroll
        for (int k2 = 0; k2 < 5; ++k2) {
          f32x2 at = *(const f32x2*)&s_att[grp][r5][k2 * 2];
          za += at[0] * w1c[2 * k2][0] + at[1] * w1c[2 * k2 + 1][0];
          zb += at[0] * w1c[2 * k2][1] + at[1] * w1c[2 * k2 + 1][1];
        }
        s_h1[grp][r5][l16 * 2]     = (__bf16)leaky(za);
        s_h1[grp][r5][l16 * 2 + 1] = (__bf16)leaky(zb);
      }
    }

    // h2: lane owns unit l16
    {
      float w2c[32];
      #pragma unroll
      for (int k = 0; k < 32; ++k) w2c[k] = w_o2[k * 16 + l16];
      const float b2 = b_o2[l16];
      #pragma unroll
      for (int r5 = 0; r5 < NL_; ++r5) {
        float z = b2;
        #pragma unroll
        for (int k4 = 0; k4 < 8; ++k4) {
          bf16x4 hv = *(const bf16x4*)&s_h1[grp][r5][k4 * 4];
          z += (float)hv[0] * w2c[4 * k4] + (float)hv[1] * w2c[4 * k4 + 1]
             + (float)hv[2] * w2c[4 * k4 + 2] + (float)hv[3] * w2c[4 * k4 + 3];
        }
        s_h2[grp][r5][l16] = leaky(z);
      }
    }

    // hp + softmax -> o5 slot in s_oin (lanes 0..4)
    if (l16 < NL_) {
      float z3 = b_o3[0];
      #pragma unroll
      for (int k4 = 0; k4 < 4; ++k4) {
        f32x4 hv = *(const f32x4*)&s_h2[grp][l16][k4 * 4];
        z3 += hv[0] * w_o3[4 * k4] + hv[1] * w_o3[4 * k4 + 1]
            + hv[2] * w_o3[4 * k4 + 2] + hv[3] * w_o3[4 * k4 + 3];
      }
      float hp_own = leaky(z3);
      s_hp[grp][l16] = hp_own;
      float m5 = -1e30f;
      #pragma unroll
      for (int j = 0; j < NL_; ++j) m5 = fmaxf(m5, s_hp[grp][j]);
      float ssum = 0.0f;
      #pragma unroll
      for (int j = 0; j < NL_; ++j) ssum += __expf(s_hp[grp][j] - m5);
      s_oin[row * 96 + 88 + l16] = (__bf16)(__expf(hp_own - m5) / ssum);
    }
  }

  __syncthreads();   // o5 ready; front scratch dead -> A_x may overwrite

  // ================= GEMM PHASE: wave wv owns rows r0..r0+15 =================
  const int l = l16;

  // hidden A-fragments direct from global
  bf16x8 ah[2];
  {
    const float* hrow_g = hidden + (gr0 + r0 + l) * HID_;
    f32x4 vha0 = *(const f32x4*)&hrow_g[quad * 8];
    f32x4 vha1 = *(const f32x4*)&hrow_g[quad * 8 + 4];
    f32x4 vhb0 = *(const f32x4*)&hrow_g[32 + quad * 8];
    f32x4 vhb1 = *(const f32x4*)&hrow_g[32 + quad * 8 + 4];
    bf16x8 t;
    t[0] = (__bf16)vha0[0]; t[1] = (__bf16)vha0[1]; t[2] = (__bf16)vha0[2]; t[3] = (__bf16)vha0[3];
    t[4] = (__bf16)vha1[0]; t[5] = (__bf16)vha1[1]; t[6] = (__bf16)vha1[2]; t[7] = (__bf16)vha1[3];
    ah[0] = t;
    t[0] = (__bf16)vhb0[0]; t[1] = (__bf16)vhb0[1]; t[2] = (__bf16)vhb0[2]; t[3] = (__bf16)vhb0[3];
    t[4] = (__bf16)vhb1[0]; t[5] = (__bf16)vhb1[1]; t[6] = (__bf16)vhb1[2]; t[7] = (__bf16)vhb1[3];
    ah[1] = t;
  }

  const f32x4 zero4 = {0.0f, 0.0f, 0.0f, 0.0f};

  // fc1: C[16x64] = s_oin[16x96] @ Wf1T -- all A-frags single aligned b128.
  f32x4 cx[4];
  #pragma unroll
  for (int nt = 0; nt < 4; ++nt) cx[nt] = zero4;
  #pragma unroll
  for (int ks = 0; ks < 3; ++ks) {
    bf16x8 af = *(const bf16x8*)&s_oin[(r0 + l) * 96 + ks * 32 + quad * 8];
    #pragma unroll
    for (int nt = 0; nt < 4; ++nt) {
      bf16x8 bf = *(const bf16x8*)&Wf1[(nt * 16 + l) * 96 + ks * 32 + quad * 8];
      cx[nt] = __builtin_amdgcn_mfma_f32_16x16x32_bf16(af, bf, cx[nt], 0, 0, 0);
    }
  }
  #pragma unroll
  for (int nt = 0; nt < 4; ++nt) {
    float bias = b_fc1[nt * 16 + l];
    #pragma unroll
    for (int rg = 0; rg < 4; ++rg) {
      float xv = fmaxf(cx[nt][rg] + bias, 0.0f);
      A_x[(r0 + quad * 4 + rg) * SXH_ + nt * 16 + l] = (__bf16)xv;
    }
  }

  // GRU GEMMs, gate-split (B-columns permuted: tile nt, lane l == orig col 4l+nt)
  bf16x8 ax[2];
  #pragma unroll
  for (int ks = 0; ks < 2; ++ks)
    ax[ks] = *(const bf16x8*)&A_x[(r0 + l) * SXH_ + ks * 32 + quad * 8];

  // ---- phase A (nt-split halves, accum peak 16): r-gates + gh_n -> rn ----
  f32x4 rn[4];
  {
    f32x4 a0 = *(const f32x4*)&b_ih[4 * l];
    f32x4 a1 = *(const f32x4*)&b_hh[4 * l];
    f32x4 br4 = a0 + a1;
    f32x4 bhn4 = *(const f32x4*)&b_hh[128 + 4 * l];
    #pragma unroll
    for (int hf = 0; hf < 2; ++hf) {
      f32x4 cr2[2], ch2[2];
      cr2[0] = zero4; cr2[1] = zero4; ch2[0] = zero4; ch2[1] = zero4;
      #pragma unroll
      for (int n2 = 0; n2 < 2; ++n2) {
        const int nt = hf * 2 + n2;
        #pragma unroll
        for (int ks = 0; ks < 2; ++ks) {
          bf16x8 bi = *(const bf16x8*)&Wih[(nt * 16 + l) * 64 + ks * 32 + quad * 8];
          cr2[n2] = __builtin_amdgcn_mfma_f32_16x16x32_bf16(ax[ks], bi, cr2[n2], 0, 0, 0);
          bf16x8 bh = *(const bf16x8*)&Whh[(nt * 16 + l) * 64 + ks * 32 + quad * 8];
          cr2[n2] = __builtin_amdgcn_mfma_f32_16x16x32_bf16(ah[ks], bh, cr2[n2], 0, 0, 0);
        }
        #pragma unroll
        for (int ks = 0; ks < 2; ++ks) {
          bf16x8 bh = *(const bf16x8*)&Whh[(128 + nt * 16 + l) * 64 + ks * 32 + quad * 8];
          ch2[n2] = __builtin_amdgcn_mfma_f32_16x16x32_bf16(ah[ks], bh, ch2[n2], 0, 0, 0);
        }
      }
      #pragma unroll
      for (int n2 = 0; n2 < 2; ++n2) {
        const int nt = hf * 2 + n2;
        #pragma unroll
        for (int rg = 0; rg < 4; ++rg) {
          float rr = sigmoidf(cr2[n2][rg] + br4[nt]);
          rn[nt][rg] = rr * (ch2[n2][rg] + bhn4[nt]);
        }
      }
    }
  }

  // ---- phase B: gi_n; retire into nn ----
  f32x4 cn[4];
  #pragma unroll
  for (int nt = 0; nt < 4; ++nt) cn[nt] = zero4;
  #pragma unroll
  for (int nt = 0; nt < 4; ++nt)
    #pragma unroll
    for (int ks = 0; ks < 2; ++ks) {
      bf16x8 bi = *(const bf16x8*)&Wih[(128 + nt * 16 + l) * 64 + ks * 32 + quad * 8];
      cn[nt] = __builtin_amdgcn_mfma_f32_16x16x32_bf16(ax[ks], bi, cn[nt], 0, 0, 0);
    }
  f32x4 nn[4];
  {
    f32x4 bin4 = *(const f32x4*)&b_ih[128 + 4 * l];
    #pragma unroll
    for (int nt = 0; nt < 4; ++nt)
      #pragma unroll
      for (int rg = 0; rg < 4; ++rg)
        nn[nt][rg] = tanh_fast(cn[nt][rg] + bin4[nt] + rn[nt][rg]);
  }

  // ---- phase C: z-gates, then h / q (per-rg retire) ----
  f32x4 cz[4];
  #pragma unroll
  for (int nt = 0; nt < 4; ++nt) cz[nt] = zero4;
  #pragma unroll
  for (int nt = 0; nt < 4; ++nt)
    #pragma unroll
    for (int ks = 0; ks < 2; ++ks) {
      bf16x8 bi = *(const bf16x8*)&Wih[(64 + nt * 16 + l) * 64 + ks * 32 + quad * 8];
      cz[nt] = __builtin_amdgcn_mfma_f32_16x16x32_bf16(ax[ks], bi, cz[nt], 0, 0, 0);
      bf16x8 bh = *(const bf16x8*)&Whh[(64 + nt * 16 + l) * 64 + ks * 32 + quad * 8];
      cz[nt] = __builtin_amdgcn_mfma_f32_16x16x32_bf16(ah[ks], bh, cz[nt], 0, 0, 0);
    }

  const long grow = gr0 + r0 + quad * 4;
  f32x4 bz4;
  {
    f32x4 a0 = *(const f32x4*)&b_ih[64 + 4 * l];
    f32x4 a1 = *(const f32x4*)&b_hh[64 + 4 * l];
    bz4 = a0 + a1;
  }
  f32x4 w20[5];
  #pragma unroll
  for (int j = 0; j < 5; ++j) w20[j] = *(const f32x4*)&w_fc2[20 * l + 4 * j];

  #pragma unroll
  for (int rg = 0; rg < 4; ++rg) {
    f32x4 hold = *(const f32x4*)&hidden[(grow + rg) * HID_ + 4 * l];
    f32x4 hnew;
    float qp5[NACT_] = {0.0f, 0.0f, 0.0f, 0.0f, 0.0f};
    #pragma unroll
    for (int t = 0; t < 4; ++t) {
      float zz = sigmoidf(cz[t][rg] + bz4[t]);
      float hn = (1.0f - zz) * nn[t][rg] + zz * hold[t];
      hnew[t] = hn;
      #pragma unroll
      for (int c = 0; c < NACT_; ++c)
        qp5[c] += hn * w20[(5 * t + c) >> 2][(5 * t + c) & 3];
    }
    *(f32x4*)&h_out[(grow + rg) * HID_ + 4 * l] = hnew;
    #pragma unroll
    for (int c = 0; c < NACT_; ++c) qp5[c] = red16(qp5[c]);
    if (l < NACT_) {
      float qv = qp5[0];
      if (l == 1) qv = qp5[1];
      if (l == 2) qv = qp5[2];
      if (l == 3) qv = qp5[3];
      if (l == 4) qv = qp5[4];
      q_out[(grow + rg) * NACT_ + l] = qv + b_fc2[l];
    }
  }
}

}  // namespace

extern "C" void kernel_launch(void* const* d_in, const int* in_sizes, int n_in,
                              void* d_out, int out_size, void* d_ws, size_t ws_size,
                              hipStream_t stream) {
  const float* obs    = (const float*)d_in[0];
  const float* hidden = (const float*)d_in[1];
  const float* w_in0  = (const float*)d_in[2];
  const float* b_in0  = (const float*)d_in[3];
  const float* w_in1  = (const float*)d_in[4];
  const float* b_in1  = (const float*)d_in[5];
  const float* w_in2  = (const float*)d_in[6];
  const float* b_in2  = (const float*)d_in[7];
  const float* W      = (const float*)d_in[8];
  const float* a      = (const float*)d_in[9];
  const float* w_o1   = (const float*)d_in[10];
  const float* b_o1   = (const float*)d_in[11];
  const float* w_o2   = (const float*)d_in[12];
  const float* b_o2   = (const float*)d_in[13];
  const float* w_o3   = (const float*)d_in[14];
  const float* b_o3   = (const float*)d_in[15];
  const float* w_fc1  = (const float*)d_in[16];
  const float* b_fc1  = (const float*)d_in[17];
  const float* w_ih   = (const float*)d_in[18];
  const float* w_hh   = (const float*)d_in[19];
  const float* b_ih   = (const float*)d_in[20];
  const float* b_hh   = (const float*)d_in[21];
  const float* w_fc2  = (const float*)d_in[22];
  const float* b_fc2  = (const float*)d_in[23];

  float* q_out = (float*)d_out;                  // (B,5)
  float* h_out = q_out + (long)B_ * NACT_;       // (B,64)

  prep_kernel<<<48, 256, 0, stream>>>(W, a, w_ih, w_hh, w_fc1, d_ws);
  fused_kernel<<<B_ / 64, 256, 0, stream>>>(
      obs, hidden,
      w_in0, b_in0, w_in1, b_in1, w_in2, b_in2,
      w_o1, b_o1, w_o2, b_o2, w_o3, b_o3,
      b_fc1, b_ih, b_hh, w_fc2, b_fc2,
      d_ws, q_out, h_out);
}

// Round 12
// 188.619 us; speedup vs baseline: 1.2490x; 1.0805x over previous
//
#include <hip/hip_runtime.h>
#include <math.h>

namespace {

typedef __bf16 bf16x8 __attribute__((ext_vector_type(8)));
typedef __bf16 bf16x4 __attribute__((ext_vector_type(4)));
typedef float  f32x4  __attribute__((ext_vector_type(4)));
typedef float  f32x2  __attribute__((ext_vector_type(2)));

constexpr int B_      = 65536;
constexpr int OBS_DIM_= 85;
constexpr int NL_     = 5;
constexpr int NT_     = 10;
constexpr int HID_    = 64;
constexpr int NACT_   = 5;
constexpr float ALPHA_= 0.01f;

__device__ __forceinline__ float leaky(float x)    { return fmaf(fminf(x, 0.0f), ALPHA_ - 1.0f, x); }
__device__ __forceinline__ float sigmoidf(float x) { return 1.0f / (1.0f + __expf(-x)); }
__device__ __forceinline__ float tanh_fast(float x){ return 1.0f - 2.0f / (__expf(2.0f * x) + 1.0f); }

// 16-lane all-reduce sum on the VALU pipe (no LDS): quad_perm xor1, xor2,
// then half-row mirror (x^7) and row mirror (x^15). After xor1+xor2 each
// quad is uniform, so the mirrors complete the 8- and 16-lane sums.
// dpp_ctrl must be an integer constant expression -> template parameter.
template <int CTRL>
__device__ __forceinline__ float dppadd(float x) {
  int y = __builtin_amdgcn_update_dpp(0, __float_as_int(x), CTRL, 0xF, 0xF, true);
  return x + __int_as_float(y);
}
__device__ __forceinline__ float red16(float x) {
  x = dppadd<0xB1>(x);    // quad_perm [1,0,3,2]  (xor 1)
  x = dppadd<0x4E>(x);    // quad_perm [2,3,0,1]  (xor 2)
  x = dppadd<0x141>(x);   // row_half_mirror      (xor 7)
  x = dppadd<0x140>(x);   // row_mirror           (xor 15)
  return x;
}

// ---------------------------------------------------------------------------
// Prep: Wa = W@a, bf16 Wih/Whh (column-permuted: permuted row nt*16+l holds
// original row 4l+nt within each 64-row gate block), bf16 Wf1T (64x96).
// Wf1T K-layout: k<85 = obs cols, k 85..87 = 0, k 88..92 = w_fc1 rows 85..89
// (the o5 inputs), k 93..95 = 0.  This makes EVERY fc1 A-fragment a single
// aligned 16B LDS read (obs rows padded to 88, o5 rows padded to 8).
// ---------------------------------------------------------------------------
__global__ void prep_kernel(const float* __restrict__ W, const float* __restrict__ a,
                            const float* __restrict__ w_ih, const float* __restrict__ w_hh,
                            const float* __restrict__ w_fc1, void* __restrict__ ws) {
  float* Wa   = (float*)ws;
  __bf16* ih  = (__bf16*)((char*)ws + 512);
  __bf16* hh  = ih + 192 * 64;
  __bf16* f1t = hh + 192 * 64;
  const int tid = blockIdx.x * 256 + threadIdx.x;
  if (blockIdx.x == 0 && threadIdx.x < 64) {
    const int i = threadIdx.x;
    float s1 = 0.0f, s2 = 0.0f;
    #pragma unroll
    for (int j = 0; j < 64; ++j) {
      float w = W[i * 64 + j];
      s1 += w * a[j];
      s2 += w * a[64 + j];
    }
    Wa[i] = s1;
    Wa[64 + i] = s2;
  }
  const int stride = gridDim.x * 256;
  for (int i = tid; i < 192 * 64; i += stride) {
    int pr = i >> 6, k = i & 63;
    int g  = pr >> 6;
    int q  = pr & 63;
    int orig = (g << 6) + ((q & 15) << 2) + (q >> 4);   // 4*l + nt
    ih[i] = (__bf16)w_ih[orig * 64 + k];
    hh[i] = (__bf16)w_hh[orig * 64 + k];
  }
  for (int i = tid; i < 64 * 96; i += stride) {
    int n = i / 96, k = i - 96 * n;
    float v = 0.0f;
    if (k < 85)                 v = w_fc1[k * 64 + n];
    else if (k >= 88 && k < 93) v = w_fc1[(85 + k - 88) * 64 + n];
    f1t[i] = (__bf16)v;
  }
}

// ======================= FUSED KERNEL =======================
// r23 = exact revert to r17 (the verified best: fused 81.4us, VGPR 108,
// zero spill, total 190.3us). Post-r17 record: every structural change
// (stage-1 MFMA r19/r20, (256,3) r21, hoisted ILP r22) flipped the
// allocator out of its 108-reg mode (to 64-84 regs, with or without spill)
// and regressed to 100-126us. Occupancy is allocator-walled at 2 blocks/CU;
// restoring the known-best codegen mode.
constexpr int SXH_ = 72;

__global__ __launch_bounds__(256, 2) void fused_kernel(
    const float* __restrict__ obs, const float* __restrict__ hidden,
    const float* __restrict__ w_in0, const float* __restrict__ b_in0,
    const float* __restrict__ w_in1, const float* __restrict__ b_in1,
    const float* __restrict__ w_in2, const float* __restrict__ b_in2,
    const float* __restrict__ w_o1, const float* __restrict__ b_o1,
    const float* __restrict__ w_o2, const float* __restrict__ b_o2,
    const float* __restrict__ w_o3, const float* __restrict__ b_o3,
    const float* __restrict__ b_fc1,
    const float* __restrict__ b_ih, const float* __restrict__ b_hh,
    const float* __restrict__ w_fc2, const float* __restrict__ b_fc2,
    const void* __restrict__ wsv,
    float* __restrict__ q_out, float* __restrict__ h_out) {

  __shared__ __align__(16) char smem[28416];
  __bf16* s_obs          = (__bf16*)smem;                       // [64][88]
  float  (*s_att)[5][10] = (float (*)[5][10])(smem + 11264);
  __bf16 (*s_h1)[5][32]  = (__bf16 (*)[5][32])(smem + 14464);
  float  (*s_h2)[5][16]  = (float (*)[5][16])(smem + 19584);
  __bf16* A_x            = (__bf16*)(smem + 11264);             // gemm-phase union
  float (*s_wh1)[12]     = (float (*)[12])(smem + 24704);
  float (*s_wh2)[12]     = (float (*)[12])(smem + 25472);
  float (*s_colm)[6]     = (float (*)[6])(smem + 26240);
  float (*s_cols)[6]     = (float (*)[6])(smem + 26624);
  float (*s_hp)[6]       = (float (*)[6])(smem + 27008);
  __bf16* s_o5           = (__bf16*)(smem + 27392);             // [64][8]

  const int tid  = threadIdx.x;
  const int wv   = tid >> 6;
  const int lane = tid & 63;
  const int l16  = lane & 15;
  const int grp  = tid >> 4;               // 0..15 (row group within a pass)
  const long gr0 = (long)blockIdx.x * 64;

  const float* Wa = (const float*)wsv;
  const __bf16* Wih = (const __bf16*)((const char*)wsv + 512);
  const __bf16* Whh = Wih + 192 * 64;
  const __bf16* Wf1 = Whh + 192 * 64;

  // ---- stage: 64 rows x 85 f32 -> bf16 LDS [64][88]; wave-local rows ----
  {
    const float* src = obs + gr0 * OBS_DIM_;
    const int base = wv * 340;                     // f32x4 chunks of this wave
    #pragma unroll
    for (int k = 0; k < 6; ++k) {
      if (k < 5 || lane < 20) {
        int c = base + k * 64 + lane;
        f32x4 v = *(const f32x4*)&src[c * 4];
        #pragma unroll
        for (int e = 0; e < 4; ++e) {
          int fe = c * 4 + e;
          int r = fe / 85, col = fe - 85 * r;
          s_obs[r * 88 + col] = (__bf16)v[e];
        }
      }
    }
    if (lane < 48) {                               // zero pads (NaN guard)
      int r = wv * 16 + lane / 3, j = lane % 3;
      s_obs[r * 88 + 85 + j] = (__bf16)0.0f;
      s_o5[r * 8 + 5 + j]    = (__bf16)0.0f;
    }
  }

  const int u0 = l16 * 4;
  const f32x4 wa1 = *(const f32x4*)&Wa[u0];
  const f32x4 wa2 = *(const f32x4*)&Wa[64 + u0];

  __syncthreads();

  // ================= FRONT PHASE: 4 passes x 16 rows =================
  #pragma unroll 1
  for (int pass = 0; pass < 4; ++pass) {
    const int row = pass * 16 + grp;                 // block-local row 0..63
    const __bf16* orow = s_obs + row * 88;

    f32x4 wA[8];
    f32x4 bA;
    #pragma unroll
    for (int t = 0; t < NT_; ++t) {
      if (t == 0) {
        #pragma unroll
        for (int f = 0; f < 8; ++f) wA[f] = *(const f32x4*)&w_in0[f * 64 + u0];
        bA = *(const f32x4*)&b_in0[u0];
      }
      if (t == 5) {
        #pragma unroll
        for (int f = 0; f < 8; ++f) wA[f] = *(const f32x4*)&w_in1[f * 64 + u0];
        bA = *(const f32x4*)&b_in1[u0];
      }
      if (t == 9) {
        #pragma unroll
        for (int f = 0; f < 8; ++f) wA[f] = *(const f32x4*)&w_in2[f * 64 + u0];
        bA = *(const f32x4*)&b_in2[u0];
      }
      const int ia = t * 8 + 4;
      int ib = t * 8 + 8;
      if (ib >= 80) ib = 0;
      bf16x4 va = *(const bf16x4*)&orow[ia];
      bf16x4 vb = *(const bf16x4*)&orow[ib];
      float oa[4], ob[4];
      #pragma unroll
      for (int e = 0; e < 4; ++e) { oa[e] = (float)va[e]; ob[e] = (float)vb[e]; }
      f32x4 z = bA;
      #pragma unroll
      for (int f = 0; f < 4; ++f) {
        z[0] += oa[f] * wA[f][0]; z[1] += oa[f] * wA[f][1];
        z[2] += oa[f] * wA[f][2]; z[3] += oa[f] * wA[f][3];
      }
      #pragma unroll
      for (int f = 4; f < 8; ++f) {
        z[0] += ob[f - 4] * wA[f][0]; z[1] += ob[f - 4] * wA[f][1];
        z[2] += ob[f - 4] * wA[f][2]; z[3] += ob[f - 4] * wA[f][3];
      }
      float h0 = leaky(z[0]), h1 = leaky(z[1]), h2 = leaky(z[2]), h3 = leaky(z[3]);
      float p1t = h0 * wa1[0] + h1 * wa1[1] + h2 * wa1[2] + h3 * wa1[3];
      float p2t = h0 * wa2[0] + h1 * wa2[1] + h2 * wa2[2] + h3 * wa2[3];
      p1t = red16(p1t);                      // VALU-pipe 16-lane reduce
      p2t = red16(p2t);
      if (l16 == 0) { s_wh1[grp][t] = p1t; s_wh2[grp][t] = p2t; }
    }

    // att1 column softmax stats (lanes 5..9)
    if (l16 >= 5 && l16 < 10) {
      const int jj = l16 - 5;
      float w1v = s_wh1[grp][NL_ + jj];
      float ev[NL_], m = -1e30f;
      #pragma unroll
      for (int k = 0; k < NL_; ++k) { ev[k] = leaky(w1v + s_wh2[grp][k]); m = fmaxf(m, ev[k]); }
      float s = 0.0f;
      #pragma unroll
      for (int k = 0; k < NL_; ++k) s += __expf(ev[k] - m);
      s_colm[grp][jj] = m;
      s_cols[grp][jj] = s;
    }

    // attention rows (lanes 0..4)
    if (l16 < NL_) {
      const int r = l16;
      const float wh1_r = s_wh1[grp][r];
      const float wh2_r = s_wh2[grp][r];
      float ev[NL_], m = -1e30f;
      #pragma unroll
      for (int j = 0; j < NL_; ++j) { ev[j] = leaky(wh1_r + s_wh2[grp][NL_ + j]); m = fmaxf(m, ev[j]); }
      float a0[NL_], s = 0.0f;
      #pragma unroll
      for (int j = 0; j < NL_; ++j) { a0[j] = __expf(ev[j] - m); s += a0[j]; }
      float inv = 1.0f / s;
      #pragma unroll
      for (int j = 0; j < NL_; ++j) s_att[grp][r][j] = a0[j] * inv;
      #pragma unroll
      for (int jj = 0; jj < NL_; ++jj) {
        float e = leaky(s_wh1[grp][NL_ + jj] + wh2_r);
        s_att[grp][r][NL_ + jj] = __expf(e - s_colm[grp][jj]) / s_cols[grp][jj];
      }
    }

    // h1: lane owns units 2*l16, 2*l16+1 (stored bf16)
    {
      f32x2 w1c[NT_];
      #pragma unroll
      for (int k = 0; k < NT_; ++k) w1c[k] = *(const f32x2*)&w_o1[k * 32 + l16 * 2];
      const f32x2 b1 = *(const f32x2*)&b_o1[l16 * 2];
      #pragma unroll
      for (int r5 = 0; r5 < NL_; ++r5) {
        float za = b1[0], zb = b1[1];
        #pragma unroll
        for (int k2 = 0; k2 < 5; ++k2) {
          f32x2 at = *(const f32x2*)&s_att[grp][r5][k2 * 2];
          za += at[0] * w1c[2 * k2][0] + at[1] * w1c[2 * k2 + 1][0];
          zb += at[0] * w1c[2 * k2][1] + at[1] * w1c[2 * k2 + 1][1];
        }
        s_h1[grp][r5][l16 * 2]     = (__bf16)leaky(za);
        s_h1[grp][r5][l16 * 2 + 1] = (__bf16)leaky(zb);
      }
    }

    // h2: lane owns unit l16
    {
      float w2c[32];
      #pragma unroll
      for (int k = 0; k < 32; ++k) w2c[k] = w_o2[k * 16 + l16];
      const float b2 = b_o2[l16];
      #pragma unroll
      for (int r5 = 0; r5 < NL_; ++r5) {
        float z = b2;
        #pragma unroll
        for (int k4 = 0; k4 < 8; ++k4) {
          bf16x4 hv = *(const bf16x4*)&s_h1[grp][r5][k4 * 4];
          z += (float)hv[0] * w2c[4 * k4] + (float)hv[1] * w2c[4 * k4 + 1]
             + (float)hv[2] * w2c[4 * k4 + 2] + (float)hv[3] * w2c[4 * k4 + 3];
        }
        s_h2[grp][r5][l16] = leaky(z);
      }
    }

    // hp + softmax -> s_o5 (lanes 0..4)
    if (l16 < NL_) {
      float z3 = b_o3[0];
      #pragma unroll
      for (int k4 = 0; k4 < 4; ++k4) {
        f32x4 hv = *(const f32x4*)&s_h2[grp][l16][k4 * 4];
        z3 += hv[0] * w_o3[4 * k4] + hv[1] * w_o3[4 * k4 + 1]
            + hv[2] * w_o3[4 * k4 + 2] + hv[3] * w_o3[4 * k4 + 3];
      }
      float hp_own = leaky(z3);
      s_hp[grp][l16] = hp_own;
      float m5 = -1e30f;
      #pragma unroll
      for (int j = 0; j < NL_; ++j) m5 = fmaxf(m5, s_hp[grp][j]);
      float ssum = 0.0f;
      #pragma unroll
      for (int j = 0; j < NL_; ++j) ssum += __expf(s_hp[grp][j] - m5);
      s_o5[row * 8 + l16] = (__bf16)(__expf(hp_own - m5) / ssum);
    }
  }

  __syncthreads();   // all o5 ready; front scratch dead -> A_x may overwrite

  // ================= GEMM PHASE: wave wv owns rows r0..r0+15 =================
  const int l    = l16;
  const int quad = lane >> 4;
  const int r0   = wv * 16;

  // hidden A-fragments direct from global
  bf16x8 ah[2];
  {
    const float* hrow_g = hidden + (gr0 + r0 + l) * HID_;
    f32x4 vha0 = *(const f32x4*)&hrow_g[quad * 8];
    f32x4 vha1 = *(const f32x4*)&hrow_g[quad * 8 + 4];
    f32x4 vhb0 = *(const f32x4*)&hrow_g[32 + quad * 8];
    f32x4 vhb1 = *(const f32x4*)&hrow_g[32 + quad * 8 + 4];
    bf16x8 t;
    t[0] = (__bf16)vha0[0]; t[1] = (__bf16)vha0[1]; t[2] = (__bf16)vha0[2]; t[3] = (__bf16)vha0[3];
    t[4] = (__bf16)vha1[0]; t[5] = (__bf16)vha1[1]; t[6] = (__bf16)vha1[2]; t[7] = (__bf16)vha1[3];
    ah[0] = t;
    t[0] = (__bf16)vhb0[0]; t[1] = (__bf16)vhb0[1]; t[2] = (__bf16)vhb0[2]; t[3] = (__bf16)vhb0[3];
    t[4] = (__bf16)vhb1[0]; t[5] = (__bf16)vhb1[1]; t[6] = (__bf16)vhb1[2]; t[7] = (__bf16)vhb1[3];
    ah[1] = t;
  }

  const f32x4 zero4 = {0.0f, 0.0f, 0.0f, 0.0f};

  // fc1: C[16x64] = [obs(85)|0(3)|o5(5)|0(3)][16x96] @ Wf1T -- all A-frags
  // are single aligned b128 reads (k-layout matches prep).
  f32x4 cx[4];
  #pragma unroll
  for (int nt = 0; nt < 4; ++nt) cx[nt] = zero4;
  #pragma unroll
  for (int ks = 0; ks < 3; ++ks) {
    bf16x8 af;
    if (ks < 2)         af = *(const bf16x8*)&s_obs[(r0 + l) * 88 + ks * 32 + quad * 8];
    else if (quad < 3)  af = *(const bf16x8*)&s_obs[(r0 + l) * 88 + 64 + quad * 8];
    else                af = *(const bf16x8*)&s_o5[(r0 + l) * 8];
    #pragma unroll
    for (int nt = 0; nt < 4; ++nt) {
      bf16x8 bf = *(const bf16x8*)&Wf1[(nt * 16 + l) * 96 + ks * 32 + quad * 8];
      cx[nt] = __builtin_amdgcn_mfma_f32_16x16x32_bf16(af, bf, cx[nt], 0, 0, 0);
    }
  }
  #pragma unroll
  for (int nt = 0; nt < 4; ++nt) {
    float bias = b_fc1[nt * 16 + l];
    #pragma unroll
    for (int rg = 0; rg < 4; ++rg) {
      float xv = fmaxf(cx[nt][rg] + bias, 0.0f);
      A_x[(r0 + quad * 4 + rg) * SXH_ + nt * 16 + l] = (__bf16)xv;
    }
  }

  // GRU GEMMs, gate-split (B-columns permuted: tile nt, lane l == orig col 4l+nt)
  bf16x8 ax[2];
  #pragma unroll
  for (int ks = 0; ks < 2; ++ks)
    ax[ks] = *(const bf16x8*)&A_x[(r0 + l) * SXH_ + ks * 32 + quad * 8];

  // ---- phase A: r-gates (gi_r+gh_r) and gh_n; retire into rn ----
  f32x4 cr[4], ch[4];
  #pragma unroll
  for (int nt = 0; nt < 4; ++nt) { cr[nt] = zero4; ch[nt] = zero4; }
  #pragma unroll
  for (int nt = 0; nt < 4; ++nt) {
    #pragma unroll
    for (int ks = 0; ks < 2; ++ks) {
      bf16x8 bi = *(const bf16x8*)&Wih[(nt * 16 + l) * 64 + ks * 32 + quad * 8];
      cr[nt] = __builtin_amdgcn_mfma_f32_16x16x32_bf16(ax[ks], bi, cr[nt], 0, 0, 0);
      bf16x8 bh = *(const bf16x8*)&Whh[(nt * 16 + l) * 64 + ks * 32 + quad * 8];
      cr[nt] = __builtin_amdgcn_mfma_f32_16x16x32_bf16(ah[ks], bh, cr[nt], 0, 0, 0);
    }
    #pragma unroll
    for (int ks = 0; ks < 2; ++ks) {
      bf16x8 bh = *(const bf16x8*)&Whh[(128 + nt * 16 + l) * 64 + ks * 32 + quad * 8];
      ch[nt] = __builtin_amdgcn_mfma_f32_16x16x32_bf16(ah[ks], bh, ch[nt], 0, 0, 0);
    }
  }
  f32x4 rn[4];
  {
    f32x4 a0 = *(const f32x4*)&b_ih[4 * l];
    f32x4 a1 = *(const f32x4*)&b_hh[4 * l];
    f32x4 br4 = a0 + a1;
    f32x4 bhn4 = *(const f32x4*)&b_hh[128 + 4 * l];
    #pragma unroll
    for (int nt = 0; nt < 4; ++nt)
      #pragma unroll
      for (int rg = 0; rg < 4; ++rg) {
        float rr = sigmoidf(cr[nt][rg] + br4[nt]);
        rn[nt][rg] = rr * (ch[nt][rg] + bhn4[nt]);
      }
  }

  // ---- phase B: gi_n; retire into nn ----
  f32x4 cn[4];
  #pragma unroll
  for (int nt = 0; nt < 4; ++nt) cn[nt] = zero4;
  #pragma unroll
  for (int nt = 0; nt < 4; ++nt)
    #pragma unroll
    for (int ks = 0; ks < 2; ++ks) {
      bf16x8 bi = *(const bf16x8*)&Wih[(128 + nt * 16 + l) * 64 + ks * 32 + quad * 8];
      cn[nt] = __builtin_amdgcn_mfma_f32_16x16x32_bf16(ax[ks], bi, cn[nt], 0, 0, 0);
    }
  f32x4 nn[4];
  {
    f32x4 bin4 = *(const f32x4*)&b_ih[128 + 4 * l];
    #pragma unroll
    for (int nt = 0; nt < 4; ++nt)
      #pragma unroll
      for (int rg = 0; rg < 4; ++rg)
        nn[nt][rg] = tanh_fast(cn[nt][rg] + bin4[nt] + rn[nt][rg]);
  }

  // ---- phase C: z-gates, then h / q (per-rg retire) ----
  f32x4 cz[4];
  #pragma unroll
  for (int nt = 0; nt < 4; ++nt) cz[nt] = zero4;
  #pragma unroll
  for (int nt = 0; nt < 4; ++nt)
    #pragma unroll
    for (int ks = 0; ks < 2; ++ks) {
      bf16x8 bi = *(const bf16x8*)&Wih[(64 + nt * 16 + l) * 64 + ks * 32 + quad * 8];
      cz[nt] = __builtin_amdgcn_mfma_f32_16x16x32_bf16(ax[ks], bi, cz[nt], 0, 0, 0);
      bf16x8 bh = *(const bf16x8*)&Whh[(64 + nt * 16 + l) * 64 + ks * 32 + quad * 8];
      cz[nt] = __builtin_amdgcn_mfma_f32_16x16x32_bf16(ah[ks], bh, cz[nt], 0, 0, 0);
    }

  const long grow = gr0 + r0 + quad * 4;
  f32x4 bz4;
  {
    f32x4 a0 = *(const f32x4*)&b_ih[64 + 4 * l];
    f32x4 a1 = *(const f32x4*)&b_hh[64 + 4 * l];
    bz4 = a0 + a1;
  }
  f32x4 w20[5];
  #pragma unroll
  for (int j = 0; j < 5; ++j) w20[j] = *(const f32x4*)&w_fc2[20 * l + 4 * j];

  #pragma unroll
  for (int rg = 0; rg < 4; ++rg) {
    f32x4 hold = *(const f32x4*)&hidden[(grow + rg) * HID_ + 4 * l];
    f32x4 hnew;
    float qp5[NACT_] = {0.0f, 0.0f, 0.0f, 0.0f, 0.0f};
    #pragma unroll
    for (int t = 0; t < 4; ++t) {
      float zz = sigmoidf(cz[t][rg] + bz4[t]);
      float hn = (1.0f - zz) * nn[t][rg] + zz * hold[t];
      hnew[t] = hn;
      #pragma unroll
      for (int c = 0; c < NACT_; ++c)
        qp5[c] += hn * w20[(5 * t + c) >> 2][(5 * t + c) & 3];
    }
    *(f32x4*)&h_out[(grow + rg) * HID_ + 4 * l] = hnew;
    #pragma unroll
    for (int c = 0; c < NACT_; ++c) qp5[c] = red16(qp5[c]);   // VALU-pipe reduce
    if (l < NACT_) {
      float qv = qp5[0];
      if (l == 1) qv = qp5[1];
      if (l == 2) qv = qp5[2];
      if (l == 3) qv = qp5[3];
      if (l == 4) qv = qp5[4];
      q_out[(grow + rg) * NACT_ + l] = qv + b_fc2[l];
    }
  }
}

}  // namespace

extern "C" void kernel_launch(void* const* d_in, const int* in_sizes, int n_in,
                              void* d_out, int out_size, void* d_ws, size_t ws_size,
                              hipStream_t stream) {
  const float* obs    = (const float*)d_in[0];
  const float* hidden = (const float*)d_in[1];
  const float* w_in0  = (const float*)d_in[2];
  const float* b_in0  = (const float*)d_in[3];
  const float* w_in1  = (const float*)d_in[4];
  const float* b_in1  = (const float*)d_in[5];
  const float* w_in2  = (const float*)d_in[6];
  const float* b_in2  = (const float*)d_in[7];
  const float* W      = (const float*)d_in[8];
  const float* a      = (const float*)d_in[9];
  const float* w_o1   = (const float*)d_in[10];
  const float* b_o1   = (const float*)d_in[11];
  const float* w_o2   = (const float*)d_in[12];
  const float* b_o2   = (const float*)d_in[13];
  const float* w_o3   = (const float*)d_in[14];
  const float* b_o3   = (const float*)d_in[15];
  const float* w_fc1  = (const float*)d_in[16];
  const float* b_fc1  = (const float*)d_in[17];
  const float* w_ih   = (const float*)d_in[18];
  const float* w_hh   = (const float*)d_in[19];
  const float* b_ih   = (const float*)d_in[20];
  const float* b_hh   = (const float*)d_in[21];
  const float* w_fc2  = (const float*)d_in[22];
  const float* b_fc2  = (const float*)d_in[23];

  float* q_out = (float*)d_out;                  // (B,5)
  float* h_out = q_out + (long)B_ * NACT_;       // (B,64)

  prep_kernel<<<48, 256, 0, stream>>>(W, a, w_ih, w_hh, w_fc1, d_ws);
  fused_kernel<<<B_ / 64, 256, 0, stream>>>(
      obs, hidden,
      w_in0, b_in0, w_in1, b_in1, w_in2, b_in2,
      w_o1, b_o1, w_o2, b_o2, w_o3, b_o3,
      b_fc1, b_ih, b_hh, w_fc2, b_fc2,
      d_ws, q_out, h_out);
}